// Round 5
// baseline (213.582 us; speedup 1.0000x reference)
//
#include <hip/hip_runtime.h>
#include <hip/hip_bf16.h>

// Problem constants (N=4096 rows, D=2048 cols, T=0.5 -> 1/T = 2)
#define NR 4096
#define DD 2048
#define INV_T 2.0f
// fp8 quantization pre-scale: a_n*32 stays in e4m3 normal range (max 32 < 448)
#define QSCALE 32.0f
// MFMA output = (32*sim_a)·(32*sim_b) accumulated = 1024*sim; colsum dot is
// likewise (32*Sa)·(32*Sb) = 1024 * true dot -> same constant for both paths.
#define ACC_TO_LOGIT (INV_T / (QSCALE * QSCALE))  // 2/1024

typedef __attribute__((ext_vector_type(2))) float floatx2;
typedef __attribute__((ext_vector_type(4))) float floatx4;
typedef __attribute__((ext_vector_type(4))) int int4v;
typedef __attribute__((ext_vector_type(8))) int int8v;

static __device__ __forceinline__ void async_copy16(const void* g, void* lds) {
  __builtin_amdgcn_global_load_lds((const __attribute__((address_space(1))) void*)g,
                                   (__attribute__((address_space(3))) void*)lds,
                                   16, 0, 0);
}

// ---------------------------------------------------------------------------
// Kernel 1: per-row L2 normalize -> fp8 e4m3 of (row * inv_norm * 32).
// mat 0 -> a8 (source), mat 1 -> b8 (bc_target), mat 2 -> c8 (raw_target).
// mat==1 rows 0..16 additionally zero zbuf = s_a(2048) | s_b(2048) | counter(1)
// (replaces a hipMemsetAsync graph node). grid (NR, 3), block 256.
// ---------------------------------------------------------------------------
__global__ __launch_bounds__(256) void normalize_kernel(
    const float* __restrict__ src, const float* __restrict__ bc,
    const float* __restrict__ raw,
    unsigned char* __restrict__ a8, unsigned char* __restrict__ b8,
    unsigned char* __restrict__ c8, float* __restrict__ zbuf) {
  const int row = blockIdx.x;
  const int mat = blockIdx.y;
  const int tid = threadIdx.x;
  const float* base = (mat == 0) ? src : ((mat == 1) ? bc : raw);
  const float4* b4 = (const float4*)(base + (size_t)row * DD);

  if (mat == 1 && row < 17) {
    const int idx = row * 256 + tid;
    if (idx < 2 * DD + 1) zbuf[idx] = 0.f;
  }

  float4 v0 = b4[tid * 2];
  float4 v1 = b4[tid * 2 + 1];
  float ss = v0.x * v0.x + v0.y * v0.y + v0.z * v0.z + v0.w * v0.w +
             v1.x * v1.x + v1.y * v1.y + v1.z * v1.z + v1.w * v1.w;
  #pragma unroll
  for (int off = 32; off > 0; off >>= 1) ss += __shfl_down(ss, off, 64);

  __shared__ float sred[4];
  __shared__ float sinv;
  if ((tid & 63) == 0) sred[tid >> 6] = ss;
  __syncthreads();
  if (tid == 0) sinv = rsqrtf(sred[0] + sred[1] + sred[2] + sred[3]);
  __syncthreads();
  const float s = sinv * QSCALE;

  // pack 8 floats -> 8 fp8 e4m3 bytes (HW cvt, RNE, OCP format on gfx950)
  int d0 = __builtin_amdgcn_cvt_pk_fp8_f32(v0.x * s, v0.y * s, 0, false);
  d0 = __builtin_amdgcn_cvt_pk_fp8_f32(v0.z * s, v0.w * s, d0, true);
  int d1 = __builtin_amdgcn_cvt_pk_fp8_f32(v1.x * s, v1.y * s, 0, false);
  d1 = __builtin_amdgcn_cvt_pk_fp8_f32(v1.z * s, v1.w * s, d1, true);
  int2 o; o.x = d0; o.y = d1;
  unsigned char* dst =
      ((mat == 0) ? a8 : ((mat == 1) ? b8 : c8)) + (size_t)row * DD + tid * 8;
  *(int2*)dst = o;
}

// ---------------------------------------------------------------------------
// Kernel 2: MX-fp8 MFMA GEMM a_n @ c_n^T with fused sum(exp(sim/T)) epilogue.
// Round-5 change: DOUBLE-BUFFERED LDS, one barrier per ktile, prefetch for
// kt+1 issued immediately AFTER the kt barrier. Rationale: round-4 counters
// showed the bound is the barrier's vmcnt(0) drain right after issuing the
// stage (full L2/HBM latency in the critical path each ktile; MfmaUtil 31%
// vs 14.7us MFMA floor). With dbuf the compiler's forced vmcnt(0) at the
// NEXT barrier lands a full compute body (~800cyc: 16 ds_read_b128 + 16
// MFMA) after the prefetch issue — latency hidden. Reads of buf[b] are
// retired before the next barrier (lgkmcnt(0) precedes s_barrier), so
// writing buf[b^1] right after the barrier is race-free.
// 128x128 tile, BK=128B, 16x16x128 f8f6f4 (identity E8M0 scales), XOR
// source-swizzled global_load_lds staging (conflict halving, round 2).
// grid (32, 32), block 256 (4 waves; each wave owns a 64x64 quadrant).
// LDS 64KB -> 2 blocks/CU (same residency as round 4).
// ---------------------------------------------------------------------------
__global__ __launch_bounds__(256, 2) void gemm_expsum_kernel(
    const unsigned char* __restrict__ a8, const unsigned char* __restrict__ c8,
    float* __restrict__ S_part) {
  __shared__ unsigned char As[2][128 * 128];  // [buf][row][chunk^(row&7)]
  __shared__ unsigned char Cs[2][128 * 128];
  const int tid = threadIdx.x;
  const int lane = tid & 63;
  const int wave = tid >> 6;
  const int wr = wave >> 1;       // wave row quadrant (0/1)
  const int wc = wave & 1;        // wave col quadrant (0/1)
  const int quad = lane >> 4;     // k-chunk-pair selector for fragments
  const int l16 = lane & 15;
  const int br = blockIdx.x, bc = blockIdx.y;

  floatx4 acc[4][4] = {};

  // staging: per matrix+buffer, 16 windows of 1KB (8 rows x 128B); 4/wave.
  // lane l -> window row l>>3, LDS chunk l&7; source chunk XOR-swizzled.
  const int wrow = lane >> 3;
  const int csrc = (lane & 7) ^ (wrow & 7);
  const unsigned char* gA[4];
  const unsigned char* gC[4];
  int ldsOff[4];
  #pragma unroll
  for (int q = 0; q < 4; q++) {
    const int m = wave * 4 + q;
    const int row = m * 8 + wrow;
    gA[q] = a8 + (size_t)(br * 128 + row) * DD + csrc * 16;
    gC[q] = c8 + (size_t)(bc * 128 + row) * DD + csrc * 16;
    ldsOff[q] = m * 1024;
  }

  // prologue: stage ktile 0 into buffer 0
  #pragma unroll
  for (int q = 0; q < 4; q++) {
    async_copy16(gA[q], &As[0][ldsOff[q]]);
    async_copy16(gC[q], &Cs[0][ldsOff[q]]);
    gA[q] += 128; gC[q] += 128;
  }

  #pragma unroll 2
  for (int kt = 0; kt < DD / 128; kt++) {
    const int b = kt & 1;
    __syncthreads();  // drains vmcnt: ktile-kt stage (issued one body ago)

    if (kt < DD / 128 - 1) {  // prefetch kt+1 into the other buffer
      #pragma unroll
      for (int q = 0; q < 4; q++) {
        async_copy16(gA[q], &As[b ^ 1][ldsOff[q]]);
        async_copy16(gC[q], &Cs[b ^ 1][ldsOff[q]]);
        gA[q] += 128; gC[q] += 128;
      }
    }

    // fragments: lane holds A[row=l16][k = quad*32 .. quad*32+32) as 8 dwords
    int8v af[4], bf[4];
    #pragma unroll
    for (int i = 0; i < 4; i++) {
      const int r = wr * 64 + i * 16 + l16;
      const int c0 = (2 * quad) ^ (r & 7);
      const int c1 = (2 * quad + 1) ^ (r & 7);
      int4v lo = *(const int4v*)&As[b][r * 128 + c0 * 16];
      int4v hi = *(const int4v*)&As[b][r * 128 + c1 * 16];
      af[i] = int8v{lo[0], lo[1], lo[2], lo[3], hi[0], hi[1], hi[2], hi[3]};
    }
    #pragma unroll
    for (int j = 0; j < 4; j++) {
      const int r = wc * 64 + j * 16 + l16;
      const int c0 = (2 * quad) ^ (r & 7);
      const int c1 = (2 * quad + 1) ^ (r & 7);
      int4v lo = *(const int4v*)&Cs[b][r * 128 + c0 * 16];
      int4v hi = *(const int4v*)&Cs[b][r * 128 + c1 * 16];
      bf[j] = int8v{lo[0], lo[1], lo[2], lo[3], hi[0], hi[1], hi[2], hi[3]};
    }
    #pragma unroll
    for (int i = 0; i < 4; i++)
      #pragma unroll
      for (int j = 0; j < 4; j++)
        acc[i][j] = __builtin_amdgcn_mfma_scale_f32_16x16x128_f8f6f4(
            af[i], bf[j], acc[i][j], 0 /*cbsz: fp8*/, 0 /*blgp: fp8*/,
            0, 0x7F7F7F7F, 0, 0x7F7F7F7F /*E8M0 identity scales*/);
    // no second barrier: dbuf makes writes to buf[b^1] safe, and the next
    // iteration's barrier orders reads-of-buf[b] vs the following restage.
  }

  // epilogue: sum exp(sim/T) over this block's 128x128 tile; acc = 1024*sim.
  float local = 0.f;
  #pragma unroll
  for (int i = 0; i < 4; i++)
    #pragma unroll
    for (int j = 0; j < 4; j++)
      #pragma unroll
      for (int r = 0; r < 4; r++)
        local += __expf(acc[i][j][r] * ACC_TO_LOGIT);
  #pragma unroll
  for (int off = 32; off > 0; off >>= 1) local += __shfl_down(local, off, 64);
  __shared__ float red[4];
  if (lane == 0) red[wave] = local;
  __syncthreads();
  if (tid == 0) S_part[br * 32 + bc] = red[0] + red[1] + red[2] + red[3];
}

// ---------------------------------------------------------------------------
// Kernel 3: column sums of a8/b8 (fp8 reads) + fused finalize via
// last-block-done counter. grid 512 blocks (2/CU for latency hiding; round-4
// had 1/CU): block b -> cols [(b&1)*1024 + t*4, +4), rows [(b>>1)*16, +16).
// Last block computes dot(s_a,s_b), sums S_part, writes the loss.
// ---------------------------------------------------------------------------
__global__ __launch_bounds__(256) void colsum_finalize_kernel(
    const unsigned char* __restrict__ a8, const unsigned char* __restrict__ b8,
    float* __restrict__ s_a, float* __restrict__ s_b,
    float* __restrict__ counter, const float* __restrict__ S_part,
    float* __restrict__ out) {
  const int tid = threadIdx.x;
  const int c0 = (blockIdx.x & 1) * 1024 + tid * 4;
  const int r0 = (blockIdx.x >> 1) * 16;

  float aa0 = 0.f, aa1 = 0.f, aa2 = 0.f, aa3 = 0.f;
  float bb0 = 0.f, bb1 = 0.f, bb2 = 0.f, bb3 = 0.f;
  #pragma unroll 4
  for (int i = 0; i < 16; i++) {
    const size_t off = (size_t)(r0 + i) * DD + c0;
    const int ra = *(const int*)(a8 + off);
    const int rb = *(const int*)(b8 + off);
    floatx2 a01 = __builtin_amdgcn_cvt_pk_f32_fp8(ra, false);
    floatx2 a23 = __builtin_amdgcn_cvt_pk_f32_fp8(ra, true);
    floatx2 b01 = __builtin_amdgcn_cvt_pk_f32_fp8(rb, false);
    floatx2 b23 = __builtin_amdgcn_cvt_pk_f32_fp8(rb, true);
    aa0 += a01[0]; aa1 += a01[1]; aa2 += a23[0]; aa3 += a23[1];
    bb0 += b01[0]; bb1 += b01[1]; bb2 += b23[0]; bb3 += b23[1];
  }
  atomicAdd(&s_a[c0 + 0], aa0); atomicAdd(&s_a[c0 + 1], aa1);
  atomicAdd(&s_a[c0 + 2], aa2); atomicAdd(&s_a[c0 + 3], aa3);
  atomicAdd(&s_b[c0 + 0], bb0); atomicAdd(&s_b[c0 + 1], bb1);
  atomicAdd(&s_b[c0 + 2], bb2); atomicAdd(&s_b[c0 + 3], bb3);

  __threadfence();   // order our atomics before the counter bump
  __syncthreads();
  __shared__ bool amLast;
  if (tid == 0) amLast = (atomicAdd(counter, 1.0f) == 511.0f);
  __syncthreads();
  if (!amLast) return;
  __threadfence();   // acquire side

  float dot = 0.f;
  for (int d = tid; d < DD; d += 256)
    dot += atomicAdd(&s_a[d], 0.f) * atomicAdd(&s_b[d], 0.f);  // coherent reads
  float se = 0.f;
  for (int i = tid; i < 1024; i += 256) se += S_part[i];  // gemm ended: plain ok

  #pragma unroll
  for (int off = 32; off > 0; off >>= 1) {
    dot += __shfl_down(dot, off, 64);
    se += __shfl_down(se, off, 64);
  }
  __shared__ float redd[4], reds[4];
  if ((tid & 63) == 0) { redd[tid >> 6] = dot; reds[tid >> 6] = se; }
  __syncthreads();
  if (tid == 0) {
    const float dt = redd[0] + redd[1] + redd[2] + redd[3];
    const float st = reds[0] + reds[1] + reds[2] + reds[3];
    out[0] = logf(st) - dt * (ACC_TO_LOGIT / ((float)NR * (float)NR));
  }
}

extern "C" void kernel_launch(void* const* d_in, const int* in_sizes, int n_in,
                              void* d_out, int out_size, void* d_ws, size_t ws_size,
                              hipStream_t stream) {
  const float* src = (const float*)d_in[0];
  const float* bc  = (const float*)d_in[1];
  const float* raw = (const float*)d_in[2];

  char* ws = (char*)d_ws;
  unsigned char* a8 = (unsigned char*)ws;                               // 8 MiB
  unsigned char* b8 = (unsigned char*)(ws + (size_t)8 * 1024 * 1024);   // 8 MiB
  unsigned char* c8 = (unsigned char*)(ws + (size_t)16 * 1024 * 1024);  // 8 MiB
  float* zbuf  = (float*)(ws + (size_t)24 * 1024 * 1024);  // s_a|s_b|counter
  float* s_a   = zbuf;
  float* s_b   = zbuf + DD;
  float* counter = zbuf + 2 * DD;
  float* S_part = (float*)(ws + (size_t)24 * 1024 * 1024 + 20480);  // 4 KiB

  normalize_kernel<<<dim3(NR, 3), 256, 0, stream>>>(src, bc, raw, a8, b8, c8, zbuf);
  gemm_expsum_kernel<<<dim3(32, 32), 256, 0, stream>>>(a8, c8, S_part);
  colsum_finalize_kernel<<<512, 256, 0, stream>>>(a8, b8, s_a, s_b, counter,
                                                  S_part, (float*)d_out);
}

// Round 6
// 178.375 us; speedup vs baseline: 1.1974x; 1.1974x over previous
//
#include <hip/hip_runtime.h>
#include <hip/hip_bf16.h>

// Problem constants (N=4096 rows, D=2048 cols, T=0.5 -> 1/T = 2)
#define NR 4096
#define DD 2048
#define INV_T 2.0f
// fp8 quantization pre-scale: a_n*32 stays in e4m3 normal range (max 32 < 448)
#define QSCALE 32.0f
// MFMA output = (32*sim_a)·(32*sim_b) accumulated = 1024*sim; colsum dot is
// likewise (32*Sa)·(32*Sb) = 1024 * true dot -> same constant for both paths.
#define ACC_TO_LOGIT (INV_T / (QSCALE * QSCALE))  // 2/1024

typedef __attribute__((ext_vector_type(2))) float floatx2;
typedef __attribute__((ext_vector_type(4))) float floatx4;
typedef __attribute__((ext_vector_type(4))) int int4v;
typedef __attribute__((ext_vector_type(8))) int int8v;

static __device__ __forceinline__ void async_copy16(const void* g, void* lds) {
  __builtin_amdgcn_global_load_lds((const __attribute__((address_space(1))) void*)g,
                                   (__attribute__((address_space(3))) void*)lds,
                                   16, 0, 0);
}

// ---------------------------------------------------------------------------
// Kernel 1: per-row L2 normalize -> fp8 e4m3 of (row * inv_norm * 32).
// mat 0 -> a8 (source), mat 1 -> b8 (bc_target), mat 2 -> c8 (raw_target).
// mat==1 rows 0..16 additionally zero zbuf = s_a(2048) | s_b(2048) | counter(1)
// (replaces a hipMemsetAsync graph node). grid (NR, 3), block 256.
// ---------------------------------------------------------------------------
__global__ __launch_bounds__(256) void normalize_kernel(
    const float* __restrict__ src, const float* __restrict__ bc,
    const float* __restrict__ raw,
    unsigned char* __restrict__ a8, unsigned char* __restrict__ b8,
    unsigned char* __restrict__ c8, float* __restrict__ zbuf) {
  const int row = blockIdx.x;
  const int mat = blockIdx.y;
  const int tid = threadIdx.x;
  const float* base = (mat == 0) ? src : ((mat == 1) ? bc : raw);
  const float4* b4 = (const float4*)(base + (size_t)row * DD);

  if (mat == 1 && row < 17) {
    const int idx = row * 256 + tid;
    if (idx < 2 * DD + 1) zbuf[idx] = 0.f;
  }

  float4 v0 = b4[tid * 2];
  float4 v1 = b4[tid * 2 + 1];
  float ss = v0.x * v0.x + v0.y * v0.y + v0.z * v0.z + v0.w * v0.w +
             v1.x * v1.x + v1.y * v1.y + v1.z * v1.z + v1.w * v1.w;
  #pragma unroll
  for (int off = 32; off > 0; off >>= 1) ss += __shfl_down(ss, off, 64);

  __shared__ float sred[4];
  __shared__ float sinv;
  if ((tid & 63) == 0) sred[tid >> 6] = ss;
  __syncthreads();
  if (tid == 0) sinv = rsqrtf(sred[0] + sred[1] + sred[2] + sred[3]);
  __syncthreads();
  const float s = sinv * QSCALE;

  // pack 8 floats -> 8 fp8 e4m3 bytes (HW cvt, RNE, OCP format on gfx950)
  int d0 = __builtin_amdgcn_cvt_pk_fp8_f32(v0.x * s, v0.y * s, 0, false);
  d0 = __builtin_amdgcn_cvt_pk_fp8_f32(v0.z * s, v0.w * s, d0, true);
  int d1 = __builtin_amdgcn_cvt_pk_fp8_f32(v1.x * s, v1.y * s, 0, false);
  d1 = __builtin_amdgcn_cvt_pk_fp8_f32(v1.z * s, v1.w * s, d1, true);
  int2 o; o.x = d0; o.y = d1;
  unsigned char* dst =
      ((mat == 0) ? a8 : ((mat == 1) ? b8 : c8)) + (size_t)row * DD + tid * 8;
  *(int2*)dst = o;
}

// ---------------------------------------------------------------------------
// Kernel 2: MX-fp8 MFMA GEMM a_n @ c_n^T with fused sum(exp(sim/T)) epilogue.
// Double-buffered LDS, one barrier per ktile, prefetch for kt+1 issued
// immediately AFTER the kt barrier (round 5; kept — gemm left the top-5).
// 128x128 tile, BK=128B, 16x16x128 f8f6f4 (identity E8M0 scales), XOR
// source-swizzled global_load_lds staging (conflict halving, round 2).
// grid (32, 32), block 256 (4 waves; each wave owns a 64x64 quadrant).
// ---------------------------------------------------------------------------
__global__ __launch_bounds__(256, 2) void gemm_expsum_kernel(
    const unsigned char* __restrict__ a8, const unsigned char* __restrict__ c8,
    float* __restrict__ S_part) {
  __shared__ unsigned char As[2][128 * 128];  // [buf][row][chunk^(row&7)]
  __shared__ unsigned char Cs[2][128 * 128];
  const int tid = threadIdx.x;
  const int lane = tid & 63;
  const int wave = tid >> 6;
  const int wr = wave >> 1;       // wave row quadrant (0/1)
  const int wc = wave & 1;        // wave col quadrant (0/1)
  const int quad = lane >> 4;     // k-chunk-pair selector for fragments
  const int l16 = lane & 15;
  const int br = blockIdx.x, bc = blockIdx.y;

  floatx4 acc[4][4] = {};

  // staging: per matrix+buffer, 16 windows of 1KB (8 rows x 128B); 4/wave.
  // lane l -> window row l>>3, LDS chunk l&7; source chunk XOR-swizzled.
  const int wrow = lane >> 3;
  const int csrc = (lane & 7) ^ (wrow & 7);
  const unsigned char* gA[4];
  const unsigned char* gC[4];
  int ldsOff[4];
  #pragma unroll
  for (int q = 0; q < 4; q++) {
    const int m = wave * 4 + q;
    const int row = m * 8 + wrow;
    gA[q] = a8 + (size_t)(br * 128 + row) * DD + csrc * 16;
    gC[q] = c8 + (size_t)(bc * 128 + row) * DD + csrc * 16;
    ldsOff[q] = m * 1024;
  }

  // prologue: stage ktile 0 into buffer 0
  #pragma unroll
  for (int q = 0; q < 4; q++) {
    async_copy16(gA[q], &As[0][ldsOff[q]]);
    async_copy16(gC[q], &Cs[0][ldsOff[q]]);
    gA[q] += 128; gC[q] += 128;
  }

  #pragma unroll 2
  for (int kt = 0; kt < DD / 128; kt++) {
    const int b = kt & 1;
    __syncthreads();  // drains vmcnt: ktile-kt stage (issued one body ago)

    if (kt < DD / 128 - 1) {  // prefetch kt+1 into the other buffer
      #pragma unroll
      for (int q = 0; q < 4; q++) {
        async_copy16(gA[q], &As[b ^ 1][ldsOff[q]]);
        async_copy16(gC[q], &Cs[b ^ 1][ldsOff[q]]);
        gA[q] += 128; gC[q] += 128;
      }
    }

    // fragments: lane holds A[row=l16][k = quad*32 .. quad*32+32) as 8 dwords
    int8v af[4], bf[4];
    #pragma unroll
    for (int i = 0; i < 4; i++) {
      const int r = wr * 64 + i * 16 + l16;
      const int c0 = (2 * quad) ^ (r & 7);
      const int c1 = (2 * quad + 1) ^ (r & 7);
      int4v lo = *(const int4v*)&As[b][r * 128 + c0 * 16];
      int4v hi = *(const int4v*)&As[b][r * 128 + c1 * 16];
      af[i] = int8v{lo[0], lo[1], lo[2], lo[3], hi[0], hi[1], hi[2], hi[3]};
    }
    #pragma unroll
    for (int j = 0; j < 4; j++) {
      const int r = wc * 64 + j * 16 + l16;
      const int c0 = (2 * quad) ^ (r & 7);
      const int c1 = (2 * quad + 1) ^ (r & 7);
      int4v lo = *(const int4v*)&Cs[b][r * 128 + c0 * 16];
      int4v hi = *(const int4v*)&Cs[b][r * 128 + c1 * 16];
      bf[j] = int8v{lo[0], lo[1], lo[2], lo[3], hi[0], hi[1], hi[2], hi[3]};
    }
    #pragma unroll
    for (int i = 0; i < 4; i++)
      #pragma unroll
      for (int j = 0; j < 4; j++)
        acc[i][j] = __builtin_amdgcn_mfma_scale_f32_16x16x128_f8f6f4(
            af[i], bf[j], acc[i][j], 0 /*cbsz: fp8*/, 0 /*blgp: fp8*/,
            0, 0x7F7F7F7F, 0, 0x7F7F7F7F /*E8M0 identity scales*/);
  }

  // epilogue: sum exp(sim/T) over this block's 128x128 tile; acc = 1024*sim.
  float local = 0.f;
  #pragma unroll
  for (int i = 0; i < 4; i++)
    #pragma unroll
    for (int j = 0; j < 4; j++)
      #pragma unroll
      for (int r = 0; r < 4; r++)
        local += __expf(acc[i][j][r] * ACC_TO_LOGIT);
  #pragma unroll
  for (int off = 32; off > 0; off >>= 1) local += __shfl_down(local, off, 64);
  __shared__ float red[4];
  if (lane == 0) red[wave] = local;
  __syncthreads();
  if (tid == 0) S_part[br * 32 + bc] = red[0] + red[1] + red[2] + red[3];
}

// ---------------------------------------------------------------------------
// Kernel 3: column sums of a8/b8 + fused finalize.
// Round-6 restructure: TWO-LEVEL reduction. Round-5 counters showed this
// kernel is atomic-throughput-bound (1M device-scope atomicAdds onto 4096
// addresses -> 59us, WRITE_SIZE 16.4MB write-through). Now 32 threads share
// each column inside a block via an LDS transpose, so each block emits only
// 512 atomics: 128 blocks x 256 threads x 2 arrays = 64K atomics (16x fewer).
// Block = 256 rows x 256 cols: thread (rt=tid>>3, ct=tid&7) accumulates 32
// col-partials over 8 rows (stride-32) in registers; stage [32][256] to LDS
// (stride 264 floats to spread banks); thread tid sums column tid over the
// 32 rt entries -> one atomicAdd per array. Last-block-done finalize.
// grid 128 blocks (8 col-groups x 16 row-groups), block 256.
// ---------------------------------------------------------------------------
__global__ __launch_bounds__(256) void colsum_finalize_kernel(
    const unsigned char* __restrict__ a8, const unsigned char* __restrict__ b8,
    float* __restrict__ s_a, float* __restrict__ s_b,
    float* __restrict__ counter, const float* __restrict__ S_part,
    float* __restrict__ out) {
  __shared__ float lds[32 * 264];
  const int tid = threadIdx.x;
  const int rt = tid >> 3;          // 0..31: row-thread
  const int ct = tid & 7;           // 0..7 : col-thread (32 cols each)
  const int cg = blockIdx.x & 7;    // col group (256 cols)
  const int rg = blockIdx.x >> 3;   // row group (256 rows)
  const int cbase = cg * 256 + ct * 32;
  const int rbase = rg * 256 + rt;

  float accA[32], accB[32];
  #pragma unroll
  for (int i = 0; i < 32; i++) { accA[i] = 0.f; accB[i] = 0.f; }

  #pragma unroll
  for (int k = 0; k < 8; k++) {
    const size_t off = (size_t)(rbase + k * 32) * DD + cbase;
    const int8v ra = *(const int8v*)(a8 + off);  // 32B coalesced (256B/8 lanes)
    const int8v rb = *(const int8v*)(b8 + off);
    #pragma unroll
    for (int u = 0; u < 8; u++) {
      floatx2 lo = __builtin_amdgcn_cvt_pk_f32_fp8(ra[u], false);
      floatx2 hi = __builtin_amdgcn_cvt_pk_f32_fp8(ra[u], true);
      accA[u * 4 + 0] += lo[0]; accA[u * 4 + 1] += lo[1];
      accA[u * 4 + 2] += hi[0]; accA[u * 4 + 3] += hi[1];
      lo = __builtin_amdgcn_cvt_pk_f32_fp8(rb[u], false);
      hi = __builtin_amdgcn_cvt_pk_f32_fp8(rb[u], true);
      accB[u * 4 + 0] += lo[0]; accB[u * 4 + 1] += lo[1];
      accB[u * 4 + 2] += hi[0]; accB[u * 4 + 3] += hi[1];
    }
  }

  // phase A: transpose-reduce accA across the 32 row-threads
  #pragma unroll
  for (int i = 0; i < 32; i += 4)
    *(floatx4*)&lds[rt * 264 + ct * 32 + i] =
        floatx4{accA[i], accA[i + 1], accA[i + 2], accA[i + 3]};
  __syncthreads();
  float sA = 0.f;
  #pragma unroll 8
  for (int r = 0; r < 32; r++) sA += lds[r * 264 + tid];
  atomicAdd(&s_a[cg * 256 + tid], sA);
  __syncthreads();  // all reads of lds done before phase B overwrites

  // phase B
  #pragma unroll
  for (int i = 0; i < 32; i += 4)
    *(floatx4*)&lds[rt * 264 + ct * 32 + i] =
        floatx4{accB[i], accB[i + 1], accB[i + 2], accB[i + 3]};
  __syncthreads();
  float sB = 0.f;
  #pragma unroll 8
  for (int r = 0; r < 32; r++) sB += lds[r * 264 + tid];
  atomicAdd(&s_b[cg * 256 + tid], sB);

  __threadfence();   // order our atomics before the counter bump
  __syncthreads();
  __shared__ bool amLast;
  if (tid == 0) amLast = (atomicAdd(counter, 1.0f) == 127.0f);
  __syncthreads();
  if (!amLast) return;
  __threadfence();   // acquire side

  float dot = 0.f;
  for (int d = tid; d < DD; d += 256)
    dot += atomicAdd(&s_a[d], 0.f) * atomicAdd(&s_b[d], 0.f);  // coherent reads
  float se = 0.f;
  for (int i = tid; i < 1024; i += 256) se += S_part[i];  // gemm ended: plain ok

  #pragma unroll
  for (int off = 32; off > 0; off >>= 1) {
    dot += __shfl_down(dot, off, 64);
    se += __shfl_down(se, off, 64);
  }
  __shared__ float redd[4], reds[4];
  if ((tid & 63) == 0) { redd[tid >> 6] = dot; reds[tid >> 6] = se; }
  __syncthreads();
  if (tid == 0) {
    const float dt = redd[0] + redd[1] + redd[2] + redd[3];
    const float st = reds[0] + reds[1] + reds[2] + reds[3];
    out[0] = logf(st) - dt * (ACC_TO_LOGIT / ((float)NR * (float)NR));
  }
}

extern "C" void kernel_launch(void* const* d_in, const int* in_sizes, int n_in,
                              void* d_out, int out_size, void* d_ws, size_t ws_size,
                              hipStream_t stream) {
  const float* src = (const float*)d_in[0];
  const float* bc  = (const float*)d_in[1];
  const float* raw = (const float*)d_in[2];

  char* ws = (char*)d_ws;
  unsigned char* a8 = (unsigned char*)ws;                               // 8 MiB
  unsigned char* b8 = (unsigned char*)(ws + (size_t)8 * 1024 * 1024);   // 8 MiB
  unsigned char* c8 = (unsigned char*)(ws + (size_t)16 * 1024 * 1024);  // 8 MiB
  float* zbuf  = (float*)(ws + (size_t)24 * 1024 * 1024);  // s_a|s_b|counter
  float* s_a   = zbuf;
  float* s_b   = zbuf + DD;
  float* counter = zbuf + 2 * DD;
  float* S_part = (float*)(ws + (size_t)24 * 1024 * 1024 + 20480);  // 4 KiB

  normalize_kernel<<<dim3(NR, 3), 256, 0, stream>>>(src, bc, raw, a8, b8, c8, zbuf);
  gemm_expsum_kernel<<<dim3(32, 32), 256, 0, stream>>>(a8, c8, S_part);
  colsum_finalize_kernel<<<128, 256, 0, stream>>>(a8, b8, s_a, s_b, counter,
                                                  S_part, (float*)d_out);
}